// Round 7
// baseline (181.120 us; speedup 1.0000x reference)
//
#include <hip/hip_runtime.h>
#include <math.h>

#define HW       262144
#define TOTSTEPS (HW / 32)
#define MROWS    100
#define NCOLS    50
#define OUTSZ    (MROWS * NCOLS)

typedef __attribute__((ext_vector_type(8))) _Float16 f16x8;
typedef __attribute__((ext_vector_type(2))) __fp16   fp16x2;   // cvt_pkrtz return type
typedef __attribute__((ext_vector_type(4))) float    f32x4;

// LDS buffer: padded rows of 144 B (128 data + 16 dup-pad).
//   A rows 0..99  -> bytes [0, 14400)        (slots 0..899, 9 per row)
//   B rows 0..49  -> bytes [14400, 21600)    (slots 900..1349)
//   dummy         -> slots 1350..1535
// 1536 slots * 16 B = 24576 B per buffer, ring of 3 (73728 B total).
#define ABYTES   14400
#define BUFBYTES 24576

typedef __attribute__((address_space(1))) const unsigned int GU32;
typedef __attribute__((address_space(3))) unsigned int LU32;

__device__ __forceinline__ const float* slot_src(int s, const float* pred,
                                                 const float* gt) {
  const float* p;
  if (s < 900) {                       // A rows 0..99
    int row = s / 9;
    int off = (s - row * 9) * 16;      // byte-in-row
    if (off > 112) off = 112;          // pad slot: dup bytes 112..127
    p = pred + (size_t)row * HW + (off >> 2);
  } else if (s < 1350) {               // B rows 0..49
    int s2 = s - 900;
    int row = s2 / 9;
    int off = (s2 - row * 9) * 16;
    if (off > 112) off = 112;
    p = gt + (size_t)row * HW + (off >> 2);
  } else {                             // dummy slots
    p = pred + ((s - 1350) & 7) * 4;
  }
  return p;
}

// f16 two-term split: hi = RTZ_f16(x), lo = RTZ_f16(x - hi).
__device__ __forceinline__ void split_f16(const float4& v0, const float4& v1,
                                          f16x8& hi, f16x8& lo) {
  float xs[8] = {v0.x, v0.y, v0.z, v0.w, v1.x, v1.y, v1.z, v1.w};
  union { fp16x2 p[4]; f16x8 v; } H, L;
#pragma unroll
  for (int j = 0; j < 4; ++j) {
    H.p[j] = __builtin_amdgcn_cvt_pkrtz(xs[2 * j], xs[2 * j + 1]);
    float l0 = xs[2 * j]     - (float)H.p[j][0];
    float l1 = xs[2 * j + 1] - (float)H.p[j][1];
    L.p[j] = __builtin_amdgcn_cvt_pkrtz(l0, l1);
  }
  hi = H.v; lo = L.v;
}

// ---------------------------------------------------------------------------
// Phase 1 (CONTROL — identical to R6): LDS-staged split-K GEMM, ring-3,
// counted vmcnt(6).
// ---------------------------------------------------------------------------
__global__ __launch_bounds__(256, 2) void dm_phase1(
    const float* __restrict__ pred, const float* __restrict__ gt,
    float* __restrict__ partial, int nblk) {
  __shared__ unsigned char smem[3 * BUFBYTES];

  const int b    = blockIdx.x;
  const int tid  = threadIdx.x;
  const int lane = tid & 63;
  const int wid  = tid >> 6;
  const int wi = wid >> 1, wj = wid & 1;
  const int g = lane >> 4, r = lane & 15;

  const int k0s = (int)(((long)b * TOTSTEPS) / nblk);
  const int k1s = (int)(((long)(b + 1) * TOTSTEPS) / nblk);
  const int nst = k1s - k0s;

  const float* srcb[6];
#pragma unroll
  for (int it = 0; it < 6; ++it) srcb[it] = slot_src(it * 256 + tid, pred, gt);

  auto STAGE = [&](unsigned char* bufb, int kf) {
#pragma unroll
    for (int it = 0; it < 6; ++it)
      __builtin_amdgcn_global_load_lds((GU32*)(srcb[it] + kf),
          (LU32*)(bufb + (it * 256 + wid * 64) * 16), 16, 0, 0);
  };

  f32x4 acc[4][2] = {};

  auto COMPUTE = [&](const unsigned char* bufb) {
    f16x8 bh[2], bl[2];
#pragma unroll
    for (int nf = 0; nf < 2; ++nf) {
      int R = wj * 32 + nf * 16 + r;
      if (R > NCOLS - 1) R = NCOLS - 1;
      const unsigned char* rowb = bufb + ABYTES + R * 144;
      float4 v0 = *(const float4*)(rowb + 32 * g);
      float4 v1 = *(const float4*)(rowb + 32 * g + 16);
      split_f16(v0, v1, bh[nf], bl[nf]);
    }
#pragma unroll
    for (int mf = 0; mf < 4; ++mf) {
      if (wi == 0 || mf < 3) {
        int R = wi * 64 + mf * 16 + r;
        if (R > MROWS - 1) R = MROWS - 1;
        const unsigned char* rowb = bufb + R * 144;
        float4 v0 = *(const float4*)(rowb + 32 * g);
        float4 v1 = *(const float4*)(rowb + 32 * g + 16);
        f16x8 ah, al;
        split_f16(v0, v1, ah, al);
#pragma unroll
        for (int nf = 0; nf < 2; ++nf) {
          acc[mf][nf] = __builtin_amdgcn_mfma_f32_16x16x32_f16(ah, bh[nf], acc[mf][nf], 0, 0, 0);
          acc[mf][nf] = __builtin_amdgcn_mfma_f32_16x16x32_f16(al, bh[nf], acc[mf][nf], 0, 0, 0);
          acc[mf][nf] = __builtin_amdgcn_mfma_f32_16x16x32_f16(ah, bl[nf], acc[mf][nf], 0, 0, 0);
        }
      }
    }
  };

  STAGE(smem, k0s << 5);
  if (nst > 1) STAGE(smem + BUFBYTES, (k0s + 1) << 5);

  int qc = 0;
  for (int s = 0; s < nst; ++s) {
    if (s + 1 < nst) asm volatile("s_waitcnt vmcnt(6)" ::: "memory");
    else             asm volatile("s_waitcnt vmcnt(0)" ::: "memory");
    __builtin_amdgcn_s_barrier();
    COMPUTE(smem + qc * BUFBYTES);
    if (s + 2 < nst) {
      int qs = qc + 2; if (qs >= 3) qs -= 3;
      STAGE(smem + qs * BUFBYTES, (k0s + s + 2) << 5);
    }
    qc = (qc == 2) ? 0 : qc + 1;
  }

#pragma unroll
  for (int mf = 0; mf < 4; ++mf) {
#pragma unroll
    for (int nf = 0; nf < 2; ++nf) {
#pragma unroll
      for (int qq = 0; qq < 4; ++qq) {
        int row = wi * 64 + mf * 16 + g * 4 + qq;
        int col = wj * 32 + nf * 16 + r;
        if (row < MROWS && col < NCOLS)
          partial[(size_t)b * OUTSZ + row * NCOLS + col] = acc[mf][nf][qq];
      }
    }
  }
}

// ---------------------------------------------------------------------------
// PROBE 1: staging-only, real scattered addresses, full ring/vmcnt/barrier.
// ---------------------------------------------------------------------------
__global__ __launch_bounds__(256, 2) void probe_stage(
    const float* __restrict__ pred, const float* __restrict__ gt,
    float* __restrict__ sink, int nblk) {
  __shared__ unsigned char smem[3 * BUFBYTES];
  const int b = blockIdx.x, tid = threadIdx.x, wid = tid >> 6;
  const int k0s = (int)(((long)b * TOTSTEPS) / nblk);
  const int k1s = (int)(((long)(b + 1) * TOTSTEPS) / nblk);
  const int nst = k1s - k0s;
  const float* srcb[6];
#pragma unroll
  for (int it = 0; it < 6; ++it) srcb[it] = slot_src(it * 256 + tid, pred, gt);
  auto STAGE = [&](unsigned char* bufb, int kf) {
#pragma unroll
    for (int it = 0; it < 6; ++it)
      __builtin_amdgcn_global_load_lds((GU32*)(srcb[it] + kf),
          (LU32*)(bufb + (it * 256 + wid * 64) * 16), 16, 0, 0);
  };
  STAGE(smem, k0s << 5);
  if (nst > 1) STAGE(smem + BUFBYTES, (k0s + 1) << 5);
  int qc = 0;
  for (int s = 0; s < nst; ++s) {
    if (s + 1 < nst) asm volatile("s_waitcnt vmcnt(6)" ::: "memory");
    else             asm volatile("s_waitcnt vmcnt(0)" ::: "memory");
    __builtin_amdgcn_s_barrier();
    if (s + 2 < nst) {
      int qs = qc + 2; if (qs >= 3) qs -= 3;
      STAGE(smem + qs * BUFBYTES, (k0s + s + 2) << 5);
    }
    qc = (qc == 2) ? 0 : qc + 1;
  }
  asm volatile("s_waitcnt lgkmcnt(0)" ::: "memory");
  float a = 0;
#pragma unroll
  for (int q = 0; q < 3; ++q)
    a += *(const float*)(smem + q * BUFBYTES + tid * 16);
  sink[b * 256 + tid] = a;
}

// ---------------------------------------------------------------------------
// PROBE 2: staging-only, CONTIGUOUS per-block slabs (same instr count, LDS
// dests, ring, barriers — only global addresses differ).
// ---------------------------------------------------------------------------
__global__ __launch_bounds__(256, 2) void probe_contig(
    const float* __restrict__ pred, float* __restrict__ sink, int nblk) {
  __shared__ unsigned char smem[3 * BUFBYTES];
  const int b = blockIdx.x, tid = threadIdx.x, wid = tid >> 6;
  const int nst = TOTSTEPS / nblk;       // 16 for nblk=512
  const float* slab = pred + (size_t)b * 49152;
  const float* srcb[6];
#pragma unroll
  for (int it = 0; it < 6; ++it) srcb[it] = slab + (it * 256 + tid) * 4;
  auto STAGE = [&](unsigned char* bufb, int kf) {
#pragma unroll
    for (int it = 0; it < 6; ++it)
      __builtin_amdgcn_global_load_lds((GU32*)(srcb[it] + kf),
          (LU32*)(bufb + (it * 256 + wid * 64) * 16), 16, 0, 0);
  };
  STAGE(smem, 0);
  if (nst > 1) STAGE(smem + BUFBYTES, 6144);
  int qc = 0;
  for (int s = 0; s < nst; ++s) {
    if (s + 1 < nst) asm volatile("s_waitcnt vmcnt(6)" ::: "memory");
    else             asm volatile("s_waitcnt vmcnt(0)" ::: "memory");
    __builtin_amdgcn_s_barrier();
    if (s + 2 < nst) {
      int qs = qc + 2; if (qs >= 3) qs -= 3;
      STAGE(smem + qs * BUFBYTES, (s + 2) * 6144);
    }
    qc = (qc == 2) ? 0 : qc + 1;
  }
  asm volatile("s_waitcnt lgkmcnt(0)" ::: "memory");
  float a = 0;
#pragma unroll
  for (int q = 0; q < 3; ++q)
    a += *(const float*)(smem + q * BUFBYTES + tid * 16);
  sink[b * 256 + tid] = a;
}

// ---------------------------------------------------------------------------
// PROBE 3: real scattered addresses -> REGISTERS. No LDS, no barriers,
// free software pipelining (max ILP/TLP for the same address stream).
// ---------------------------------------------------------------------------
__global__ __launch_bounds__(256) void probe_gldreg(
    const float* __restrict__ pred, const float* __restrict__ gt,
    float* __restrict__ sink, int nblk) {
  const int b = blockIdx.x, tid = threadIdx.x;
  const int k0s = (int)(((long)b * TOTSTEPS) / nblk);
  const int k1s = (int)(((long)(b + 1) * TOTSTEPS) / nblk);
  const int nst = k1s - k0s;
  const float* srcb[6];
#pragma unroll
  for (int it = 0; it < 6; ++it) srcb[it] = slot_src(it * 256 + tid, pred, gt);
  float a[6] = {0, 0, 0, 0, 0, 0};
  for (int s = 0; s < nst; ++s) {
    int kf = (k0s + s) << 5;
#pragma unroll
    for (int it = 0; it < 6; ++it) {
      float4 v = *(const float4*)(srcb[it] + kf);
      a[it] += v.x + v.y + v.z + v.w;
    }
  }
  sink[b * 256 + tid] = a[0] + a[1] + a[2] + a[3] + a[4] + a[5];
}

// ---------------------------------------------------------------------------
// PROBE 4: frozen-address staging (L1/L2-hot) + full compute. Measures the
// compute + barrier + LDS floor of the current structure.
// ---------------------------------------------------------------------------
__global__ __launch_bounds__(256, 2) void probe_comp(
    const float* __restrict__ pred, const float* __restrict__ gt,
    float* __restrict__ sink, int nblk) {
  __shared__ unsigned char smem[3 * BUFBYTES];
  const int b    = blockIdx.x;
  const int tid  = threadIdx.x;
  const int lane = tid & 63;
  const int wid  = tid >> 6;
  const int wi = wid >> 1, wj = wid & 1;
  const int g = lane >> 4, r = lane & 15;
  const int k0s = (int)(((long)b * TOTSTEPS) / nblk);
  const int k1s = (int)(((long)(b + 1) * TOTSTEPS) / nblk);
  const int nst = k1s - k0s;
  const float* srcb[6];
#pragma unroll
  for (int it = 0; it < 6; ++it) srcb[it] = slot_src(it * 256 + tid, pred, gt);
  auto STAGE = [&](unsigned char* bufb) {        // kf frozen at k0s
#pragma unroll
    for (int it = 0; it < 6; ++it)
      __builtin_amdgcn_global_load_lds((GU32*)(srcb[it] + (k0s << 5)),
          (LU32*)(bufb + (it * 256 + wid * 64) * 16), 16, 0, 0);
  };
  f32x4 acc[4][2] = {};
  auto COMPUTE = [&](const unsigned char* bufb) {
    f16x8 bh[2], bl[2];
#pragma unroll
    for (int nf = 0; nf < 2; ++nf) {
      int R = wj * 32 + nf * 16 + r;
      if (R > NCOLS - 1) R = NCOLS - 1;
      const unsigned char* rowb = bufb + ABYTES + R * 144;
      float4 v0 = *(const float4*)(rowb + 32 * g);
      float4 v1 = *(const float4*)(rowb + 32 * g + 16);
      split_f16(v0, v1, bh[nf], bl[nf]);
    }
#pragma unroll
    for (int mf = 0; mf < 4; ++mf) {
      if (wi == 0 || mf < 3) {
        int R = wi * 64 + mf * 16 + r;
        if (R > MROWS - 1) R = MROWS - 1;
        const unsigned char* rowb = bufb + R * 144;
        float4 v0 = *(const float4*)(rowb + 32 * g);
        float4 v1 = *(const float4*)(rowb + 32 * g + 16);
        f16x8 ah, al;
        split_f16(v0, v1, ah, al);
#pragma unroll
        for (int nf = 0; nf < 2; ++nf) {
          acc[mf][nf] = __builtin_amdgcn_mfma_f32_16x16x32_f16(ah, bh[nf], acc[mf][nf], 0, 0, 0);
          acc[mf][nf] = __builtin_amdgcn_mfma_f32_16x16x32_f16(al, bh[nf], acc[mf][nf], 0, 0, 0);
          acc[mf][nf] = __builtin_amdgcn_mfma_f32_16x16x32_f16(ah, bl[nf], acc[mf][nf], 0, 0, 0);
        }
      }
    }
  };
  STAGE(smem);
  if (nst > 1) STAGE(smem + BUFBYTES);
  int qc = 0;
  for (int s = 0; s < nst; ++s) {
    if (s + 1 < nst) asm volatile("s_waitcnt vmcnt(6)" ::: "memory");
    else             asm volatile("s_waitcnt vmcnt(0)" ::: "memory");
    __builtin_amdgcn_s_barrier();
    COMPUTE(smem + qc * BUFBYTES);
    if (s + 2 < nst) {
      int qs = qc + 2; if (qs >= 3) qs -= 3;
      STAGE(smem + qs * BUFBYTES);
    }
    qc = (qc == 2) ? 0 : qc + 1;
  }
#pragma unroll
  for (int mf = 0; mf < 4; ++mf)
#pragma unroll
    for (int nf = 0; nf < 2; ++nf)
#pragma unroll
      for (int qq = 0; qq < 4; ++qq) {
        int row = wi * 64 + mf * 16 + g * 4 + qq;
        int col = wj * 32 + nf * 16 + r;
        if (row < MROWS && col < NCOLS)
          sink[(size_t)b * OUTSZ + row * NCOLS + col] = acc[mf][nf][qq];
      }
}

// ---------------------------------------------------------------------------
// Phase 2a / 2b unchanged.
// ---------------------------------------------------------------------------
template <int NB>
__global__ void dm_reduce(const float* __restrict__ partial,
                          double* __restrict__ la0) {
  const int tid = threadIdx.x, wid = tid >> 6, lane = tid & 63;
  const int pbase = blockIdx.x * 16 + wid * 4;
  if (pbase >= OUTSZ) return;
  constexpr int IT = NB / 64;
  float4 v[IT];
#pragma unroll
  for (int i = 0; i < IT; ++i)
    v[i] = *(const float4*)(partial + (size_t)(lane + 64 * i) * OUTSZ + pbase);
  double d0 = 0, d1 = 0, d2 = 0, d3 = 0;
#pragma unroll
  for (int i = 0; i < IT; ++i) {
    d0 += (double)v[i].x; d1 += (double)v[i].y;
    d2 += (double)v[i].z; d3 += (double)v[i].w;
  }
#pragma unroll
  for (int off = 32; off; off >>= 1) {
    d0 += __shfl_xor(d0, off);
    d1 += __shfl_xor(d1, off);
    d2 += __shfl_xor(d2, off);
    d3 += __shfl_xor(d3, off);
  }
  if (lane == 0) {
    la0[pbase + 0] = (d0 - 1.0) * 10.0;
    la0[pbase + 1] = (d1 - 1.0) * 10.0;
    la0[pbase + 2] = (d2 - 1.0) * 10.0;
    la0[pbase + 3] = (d3 - 1.0) * 10.0;
  }
}

__global__ __launch_bounds__(256) void dm_sinkhorn(const double* __restrict__ la_in,
                                                   float* __restrict__ out) {
  __shared__ double la[OUTSZ];
  __shared__ double rp[MROWS];
  __shared__ double cp[NCOLS];
  const int t = threadIdx.x;
  for (int p = t; p < OUTSZ; p += 256) la[p] = la_in[p];
  if (t < NCOLS) cp[t] = 0.0;
  __syncthreads();
  for (int it = 0; it < 5; ++it) {
    if (t < 2 * MROWS) {
      int row = t >> 1, sl = t & 1;
      double m = -1e300;
      for (int j = sl; j < NCOLS; j += 2) m = fmax(m, la[row * NCOLS + j] - cp[j]);
      float s = 0.f;
      for (int j = sl; j < NCOLS; j += 2)
        s += __expf((float)(la[row * NCOLS + j] - cp[j] - m));
      double mo = __shfl_xor(m, 1); float so = __shfl_xor(s, 1);
      double mn = fmax(m, mo);
      s = s * __expf((float)(m - mn)) + so * __expf((float)(mo - mn));
      if (sl == 0) rp[row] = mn + (double)__logf(s);
    }
    __syncthreads();
    if (t < 4 * NCOLS) {
      int col = t >> 2, sl = t & 3;
      double m = -1e300;
      for (int i = sl; i < MROWS; i += 4) m = fmax(m, la[i * NCOLS + col] - rp[i]);
      float s = 0.f;
      for (int i = sl; i < MROWS; i += 4)
        s += __expf((float)(la[i * NCOLS + col] - rp[i] - m));
#pragma unroll
      for (int off = 1; off < 4; off <<= 1) {
        double mo = __shfl_xor(m, off); float so = __shfl_xor(s, off);
        double mn = fmax(m, mo);
        s = s * __expf((float)(m - mn)) + so * __expf((float)(mo - mn));
        m = mn;
      }
      if (sl == 0) cp[col] = m + (double)__logf(s);
    }
    __syncthreads();
  }
  for (int p = t; p < OUTSZ; p += 256)
    out[p] = __expf((float)(la[p] - rp[p / NCOLS] - cp[p % NCOLS]));
}

extern "C" void kernel_launch(void* const* d_in, const int* in_sizes, int n_in,
                              void* d_out, int out_size, void* d_ws, size_t ws_size,
                              hipStream_t stream) {
  const float* pred = (const float*)d_in[0];   // [1,100,512,512] fp32
  const float* gt   = (const float*)d_in[1];   // [50,512,512]    fp32
  float* out = (float*)d_out;                  // [1,100,50]      fp32

  auto fits = [&](int nb) {
    return ((size_t)nb * OUTSZ * sizeof(float) + OUTSZ * sizeof(double)) <= ws_size;
  };
  int nblk = fits(512) ? 512 : 256;

  float*  partial = (float*)d_ws;
  double* la0 = (double*)((char*)d_ws + (size_t)nblk * OUTSZ * sizeof(float));

  dm_phase1<<<nblk, 256, 0, stream>>>(pred, gt, partial, nblk);
  if (nblk == 512) dm_reduce<512><<<(OUTSZ + 15) / 16, 256, 0, stream>>>(partial, la0);
  else             dm_reduce<256><<<(OUTSZ + 15) / 16, 256, 0, stream>>>(partial, la0);
  dm_sinkhorn<<<1, 256, 0, stream>>>(la0, out);

  // ---- measurement probes (write only to dead `partial` region) ----
  float* sink = partial;
  probe_stage <<<nblk, 256, 0, stream>>>(pred, gt, sink, nblk);
  probe_contig<<<nblk, 256, 0, stream>>>(pred, sink, nblk);
  probe_gldreg<<<nblk, 256, 0, stream>>>(pred, gt, sink, nblk);
  probe_comp  <<<nblk, 256, 0, stream>>>(pred, gt, sink, nblk);
}

// Round 8
// 124.092 us; speedup vs baseline: 1.4596x; 1.4596x over previous
//
#include <hip/hip_runtime.h>
#include <math.h>

#define HW       262144
#define TOTSTEPS (HW / 32)
#define MROWS    100
#define NCOLS    50
#define OUTSZ    (MROWS * NCOLS)

typedef __attribute__((ext_vector_type(8))) _Float16 f16x8;
typedef __attribute__((ext_vector_type(2))) __fp16   fp16x2;   // cvt_pkrtz return type
typedef __attribute__((ext_vector_type(4))) float    f32x4;

// LDS buffer: padded rows of 144 B (128 data + 16 pad).
//   A rows 0..99  -> bytes [0, 14400)
//   B rows 0..49  -> bytes [14400, 21600)
// 24576 B per buffer, double-buffered (49152 B total).
// Row stride 144 B -> ds_read_b128 banks spread, conflict-free enough (2-way).
#define ABYTES   14400
#define BUFBYTES 24576

// f16 two-term split: hi = RTZ_f16(x), lo = RTZ_f16(x - hi).
__device__ __forceinline__ void split_f16(const float4& v0, const float4& v1,
                                          f16x8& hi, f16x8& lo) {
  float xs[8] = {v0.x, v0.y, v0.z, v0.w, v1.x, v1.y, v1.z, v1.w};
  union { fp16x2 p[4]; f16x8 v; } H, L;
#pragma unroll
  for (int j = 0; j < 4; ++j) {
    H.p[j] = __builtin_amdgcn_cvt_pkrtz(xs[2 * j], xs[2 * j + 1]);
    float l0 = xs[2 * j]     - (float)H.p[j][0];
    float l1 = xs[2 * j + 1] - (float)H.p[j][1];
    L.p[j] = __builtin_amdgcn_cvt_pkrtz(l0, l1);
  }
  hi = H.v; lo = L.v;
}

// ---------------------------------------------------------------------------
// Phase 1: split-K GEMM, 768 blocks (3/CU), 4 waves (2x2 grid), BK=32 fp32.
// REGISTER-staged (T14): global_load_dwordx4 -> regs -> ds_write_b128.
// 2x-unrolled static reg ping-pong:
//   WRITE(other, r_next); LOADREG(r_next2, s+2); COMPUTE(cur); syncthreads.
// Loads consumed one full compute phase after issue.
// ---------------------------------------------------------------------------
__global__ __launch_bounds__(256, 3) void dm_phase1(
    const float* __restrict__ pred, const float* __restrict__ gt,
    float* __restrict__ partial, int nblk) {
  __shared__ unsigned char smem[2 * BUFBYTES];

  const int b    = blockIdx.x;
  const int tid  = threadIdx.x;
  const int lane = tid & 63;
  const int wid  = tid >> 6;
  const int wi = wid >> 1, wj = wid & 1;
  const int g = lane >> 4, r = lane & 15;

  const int k0s = (int)(((long)b * TOTSTEPS) / nblk);
  const int k1s = (int)(((long)(b + 1) * TOTSTEPS) / nblk);
  const int nst = k1s - k0s;

  // per-thread staging slots: slot = it*256 + tid, 1350 real slots
  // (A: 9 x 16B per row x 100, B: 9 x 16B per row x 50). off clamped to 112
  // for the 9th slot (dup write of same data to same LDS addr -> benign).
  const float* srcp[6];
  int   ldso[6];
  bool  ok[6];
#pragma unroll
  for (int it = 0; it < 6; ++it) {
    int s = it * 256 + tid;
    ok[it] = s < 1350;
    int row, off;
    const float* base;
    int lbase;
    if (s < 900)      { row = s / 9;         off = (s - row * 9) * 16;       base = pred; lbase = 0; }
    else              { int s2 = s - 900;
                        row = s2 / 9;        off = (s2 - row * 9) * 16;      base = gt;   lbase = ABYTES;
                        if (s >= 1350) { row = 0; off = 0; } }
    int soff = off > 112 ? 112 : off;       // global src clamp (stay in-row)
    srcp[it] = base + (size_t)row * HW + (soff >> 2);
    ldso[it] = lbase + row * 144 + soff;    // dup-addr for 9th slot: same data
  }

  auto LOADREG = [&](float4 (&rg)[6], int kf) {
#pragma unroll
    for (int it = 0; it < 6; ++it)
      if (ok[it]) rg[it] = *(const float4*)(srcp[it] + kf);
  };
  auto WRITE = [&](unsigned char* bufb, float4 (&rg)[6]) {
#pragma unroll
    for (int it = 0; it < 6; ++it)
      if (ok[it]) *(float4*)(bufb + ldso[it]) = rg[it];
  };

  f32x4 acc[4][2] = {};

  auto COMPUTE = [&](const unsigned char* bufb) {
    f16x8 bh[2], bl[2];
#pragma unroll
    for (int nf = 0; nf < 2; ++nf) {
      int R = wj * 32 + nf * 16 + r;
      if (R > NCOLS - 1) R = NCOLS - 1;    // clamped cols -> outputs discarded
      const unsigned char* rowb = bufb + ABYTES + R * 144;
      float4 v0 = *(const float4*)(rowb + 32 * g);
      float4 v1 = *(const float4*)(rowb + 32 * g + 16);
      split_f16(v0, v1, bh[nf], bl[nf]);
    }
#pragma unroll
    for (int mf = 0; mf < 4; ++mf) {
      if (wi == 0 || mf < 3) {             // rows 112..127 don't exist
        int R = wi * 64 + mf * 16 + r;
        if (R > MROWS - 1) R = MROWS - 1;  // clamped rows -> outputs discarded
        const unsigned char* rowb = bufb + R * 144;
        float4 v0 = *(const float4*)(rowb + 32 * g);
        float4 v1 = *(const float4*)(rowb + 32 * g + 16);
        f16x8 ah, al;
        split_f16(v0, v1, ah, al);
#pragma unroll
        for (int nf = 0; nf < 2; ++nf) {
          acc[mf][nf] = __builtin_amdgcn_mfma_f32_16x16x32_f16(ah, bh[nf], acc[mf][nf], 0, 0, 0);
          acc[mf][nf] = __builtin_amdgcn_mfma_f32_16x16x32_f16(al, bh[nf], acc[mf][nf], 0, 0, 0);
          acc[mf][nf] = __builtin_amdgcn_mfma_f32_16x16x32_f16(ah, bl[nf], acc[mf][nf], 0, 0, 0);
        }
      }
    }
  };

  unsigned char* buf0 = smem;
  unsigned char* buf1 = smem + BUFBYTES;

  // prologue: stage 0 -> buf0; stage 1 -> regs (in flight)
  float4 ra[6], rb[6];
  LOADREG(ra, k0s << 5);
  WRITE(buf0, ra);                          // auto vmcnt waits on ra
  if (nst > 1) LOADREG(rb, (k0s + 1) << 5);
  __syncthreads();

  for (int s = 0; s < nst; s += 2) {
    // even half: compute stage s from buf0; rb holds stage s+1
    if (s + 1 < nst) {
      WRITE(buf1, rb);
      if (s + 2 < nst) LOADREG(ra, (k0s + s + 2) << 5);
    }
    COMPUTE(buf0);
    __syncthreads();
    if (s + 1 >= nst) break;
    // odd half: compute stage s+1 from buf1; ra holds stage s+2
    if (s + 2 < nst) {
      WRITE(buf0, ra);
      if (s + 3 < nst) LOADREG(rb, (k0s + s + 3) << 5);
    }
    COMPUTE(buf1);
    __syncthreads();
  }

  // epilogue: C/D layout col = lane&15, row = 4*(lane>>4)+reg
#pragma unroll
  for (int mf = 0; mf < 4; ++mf) {
#pragma unroll
    for (int nf = 0; nf < 2; ++nf) {
#pragma unroll
      for (int qq = 0; qq < 4; ++qq) {
        int row = wi * 64 + mf * 16 + g * 4 + qq;
        int col = wj * 32 + nf * 16 + r;
        if (row < MROWS && col < NCOLS)
          partial[(size_t)b * OUTSZ + row * NCOLS + col] = acc[mf][nf][qq];
      }
    }
  }
}

// ---------------------------------------------------------------------------
// Phase 2a: sum partials over blocks. One wave per 4 consecutive p; all NB/64
// float4 loads issued independently, reduce in double.
// ---------------------------------------------------------------------------
template <int NB>
__global__ void dm_reduce(const float* __restrict__ partial,
                          double* __restrict__ la0) {
  const int tid = threadIdx.x, wid = tid >> 6, lane = tid & 63;
  const int pbase = blockIdx.x * 16 + wid * 4;
  if (pbase >= OUTSZ) return;
  constexpr int IT = NB / 64;
  float4 v[IT];
#pragma unroll
  for (int i = 0; i < IT; ++i)
    v[i] = *(const float4*)(partial + (size_t)(lane + 64 * i) * OUTSZ + pbase);
  double d0 = 0, d1 = 0, d2 = 0, d3 = 0;
#pragma unroll
  for (int i = 0; i < IT; ++i) {
    d0 += (double)v[i].x; d1 += (double)v[i].y;
    d2 += (double)v[i].z; d3 += (double)v[i].w;
  }
#pragma unroll
  for (int off = 32; off; off >>= 1) {
    d0 += __shfl_xor(d0, off);
    d1 += __shfl_xor(d1, off);
    d2 += __shfl_xor(d2, off);
    d3 += __shfl_xor(d3, off);
  }
  if (lane == 0) {
    la0[pbase + 0] = (d0 - 1.0) * 10.0;     // -(1-dot)/0.1
    la0[pbase + 1] = (d1 - 1.0) * 10.0;
    la0[pbase + 2] = (d2 - 1.0) * 10.0;
    la0[pbase + 3] = (d3 - 1.0) * 10.0;
  }
}

// ---------------------------------------------------------------------------
// Phase 2b: Sinkhorn via dual potentials (double), fast __expf on f32 deltas.
// ---------------------------------------------------------------------------
__global__ __launch_bounds__(256) void dm_sinkhorn(const double* __restrict__ la_in,
                                                   float* __restrict__ out) {
  __shared__ double la[OUTSZ];
  __shared__ double rp[MROWS];
  __shared__ double cp[NCOLS];
  const int t = threadIdx.x;
  for (int p = t; p < OUTSZ; p += 256) la[p] = la_in[p];
  if (t < NCOLS) cp[t] = 0.0;
  __syncthreads();
  for (int it = 0; it < 5; ++it) {
    if (t < 2 * MROWS) {                    // rows: 2 lanes per row
      int row = t >> 1, sl = t & 1;
      double m = -1e300;
      for (int j = sl; j < NCOLS; j += 2) m = fmax(m, la[row * NCOLS + j] - cp[j]);
      float s = 0.f;
      for (int j = sl; j < NCOLS; j += 2)
        s += __expf((float)(la[row * NCOLS + j] - cp[j] - m));
      double mo = __shfl_xor(m, 1); float so = __shfl_xor(s, 1);
      double mn = fmax(m, mo);
      s = s * __expf((float)(m - mn)) + so * __expf((float)(mo - mn));
      if (sl == 0) rp[row] = mn + (double)__logf(s);
    }
    __syncthreads();
    if (t < 4 * NCOLS) {                    // cols: 4 lanes per col
      int col = t >> 2, sl = t & 3;
      double m = -1e300;
      for (int i = sl; i < MROWS; i += 4) m = fmax(m, la[i * NCOLS + col] - rp[i]);
      float s = 0.f;
      for (int i = sl; i < MROWS; i += 4)
        s += __expf((float)(la[i * NCOLS + col] - rp[i] - m));
#pragma unroll
      for (int off = 1; off < 4; off <<= 1) {
        double mo = __shfl_xor(m, off); float so = __shfl_xor(s, off);
        double mn = fmax(m, mo);
        s = s * __expf((float)(m - mn)) + so * __expf((float)(mo - mn));
        m = mn;
      }
      if (sl == 0) cp[col] = m + (double)__logf(s);
    }
    __syncthreads();
  }
  for (int p = t; p < OUTSZ; p += 256)
    out[p] = __expf((float)(la[p] - rp[p / NCOLS] - cp[p % NCOLS]));
}

extern "C" void kernel_launch(void* const* d_in, const int* in_sizes, int n_in,
                              void* d_out, int out_size, void* d_ws, size_t ws_size,
                              hipStream_t stream) {
  const float* pred = (const float*)d_in[0];   // [1,100,512,512] fp32
  const float* gt   = (const float*)d_in[1];   // [50,512,512]    fp32
  float* out = (float*)d_out;                  // [1,100,50]      fp32

  auto fits = [&](int nb) {
    return ((size_t)nb * OUTSZ * sizeof(float) + OUTSZ * sizeof(double)) <= ws_size;
  };
  int nblk = fits(768) ? 768 : (fits(512) ? 512 : 256);

  float*  partial = (float*)d_ws;
  double* la0 = (double*)((char*)d_ws + (size_t)nblk * OUTSZ * sizeof(float));

  dm_phase1<<<nblk, 256, 0, stream>>>(pred, gt, partial, nblk);
  if (nblk == 768)      dm_reduce<768><<<(OUTSZ + 15) / 16, 256, 0, stream>>>(partial, la0);
  else if (nblk == 512) dm_reduce<512><<<(OUTSZ + 15) / 16, 256, 0, stream>>>(partial, la0);
  else                  dm_reduce<256><<<(OUTSZ + 15) / 16, 256, 0, stream>>>(partial, la0);
  dm_sinkhorn<<<1, 256, 0, stream>>>(la0, out);
}